// Round 5
// baseline (301.558 us; speedup 1.0000x reference)
//
#include <hip/hip_runtime.h>

using f32x4 = __attribute__((ext_vector_type(4))) float;
using s16x8 = __attribute__((ext_vector_type(8))) short;
using u16x4 = __attribute__((ext_vector_type(4))) ushort;

constexpr int NB   = 16;    // batch
constexpr int CH   = 256;   // channels
constexpr int TT   = 4096;  // time
constexpr int NT   = 64;    // tokens per tile
constexpr int HALO = 8;     // (K-1)*DIL
constexpr int XROWS = NT + HALO;     // 72
constexpr int ROWB  = 512;           // bytes per LDS row (256 ch * 2B, swizzled)

__device__ __forceinline__ ushort f2b(float f) {
    unsigned u; __builtin_memcpy(&u, &f, 4);
    u += 0x7FFFu + ((u >> 16) & 1u);   // RNE
    return (ushort)(u >> 16);
}
__device__ __forceinline__ float fast_sigmoid(float x) {
    return __builtin_amdgcn_rcpf(1.f + __expf(-x));
}
__device__ __forceinline__ float fast_tanh(float x) {
    return 2.f * __builtin_amdgcn_rcpf(1.f + __expf(-2.f * x)) - 1.f;
}
// XOR swizzle: row stride 512B == 0 (mod 128B); spread rows across the 8
// 16B slots of the bank array. Keeps 16B alignment (only bits 4..6 flip).
__device__ __forceinline__ int swz(int row, int colB) {
    return row * ROWB + (colB ^ ((row & 7) << 4));
}

// Weight prep: f32 -> bf16.
// W1[m][k]: m<256 filter / m>=256 gate, k = tap*256 + in_ch.
// W2[m][i]: m<256 res / m>=256 skip.
__global__ __launch_bounds__(512)
void prep_w(const float* __restrict__ wf, const float* __restrict__ wg,
            const float* __restrict__ wr, const float* __restrict__ wsk,
            ushort* __restrict__ W1, ushort* __restrict__ W2) {
    int g = blockIdx.x * 512 + threadIdx.x;
    if (g < 512 * 64) {                       // W1: 512 rows x 64 threads (4 i each)
        int m = g >> 6, i0 = (g & 63) * 4;
        const float* src = (m < 256) ? wf + ((size_t)m << 9)
                                     : wg + ((size_t)(m - 256) << 9);
        f32x4 a = *(const f32x4*)&src[i0 * 2];
        f32x4 c = *(const f32x4*)&src[i0 * 2 + 4];
        u16x4 t0v = { f2b(a[0]), f2b(a[2]), f2b(c[0]), f2b(c[2]) };
        u16x4 t1v = { f2b(a[1]), f2b(a[3]), f2b(c[1]), f2b(c[3]) };
        *(u16x4*)&W1[(size_t)m * 512 + i0]       = t0v;   // tap 0 block
        *(u16x4*)&W1[(size_t)m * 512 + 256 + i0] = t1v;   // tap 1 block
    } else {                                  // W2: 512 rows x 64 threads
        int g2 = g - 512 * 64;
        int m = g2 >> 6, i0 = (g2 & 63) * 4;
        const float* src = (m < 256) ? wr + ((size_t)m << 8)
                                     : wsk + ((size_t)(m - 256) << 8);
        f32x4 a = *(const f32x4*)&src[i0];
        u16x4 o = { f2b(a[0]), f2b(a[1]), f2b(a[2]), f2b(a[3]) };
        *(u16x4*)&W2[(size_t)m * 256 + i0] = o;
    }
}

// 1024 blocks x 512 threads (8 waves). Block = 64-token tile, full model.
// Wave ws owns 64 M-rows: filter ch [ws*32, ws*32+32) + paired gate rows.
// acc[4 token-tiles][4 ch-tiles] = 64 AGPR; <=128 total regs -> 4 waves/SIMD,
// 2 independent blocks/CU (decoupled barrier domains). Each x-fragment read
// feeds 4 MFMAs (64 channels) -> LDS read traffic back to the R2 rate.
// MFMA roles: A = x-fragment (M=16 tokens), B = W-fragment (N=16 out-ch)
// => D: row = quad*4+r = token, col = lane&15 = channel.
__global__ __launch_bounds__(512, 4)
void fused_block(const float* __restrict__ x,
                 const ushort* __restrict__ W1, const ushort* __restrict__ W2,
                 const float* __restrict__ b_filt, const float* __restrict__ b_gate,
                 const float* __restrict__ b_res,  const float* __restrict__ b_skip,
                 float* __restrict__ out) {
    // rows 0..71: x[token][channel] bf16 swizzled (token = t0-8+row);
    // after GEMM1, rows 0..63 are reused for z[token][channel].
    __shared__ __align__(16) char lds[XROWS * ROWB];   // 36864 B

    const int tid = threadIdx.x;
    const int b  = blockIdx.x >> 6;           // 64 tiles per batch
    const int t0 = (blockIdx.x & 63) * NT;
    const float* X = x + (size_t)b * CH * TT;
    const int tg0 = t0 - HALO;

    // ---------------- stage x (f32 -> bf16, transposed, swizzled) ----------------
    {
        const int tc4 = tid & 3;          // 4-token chunk
        const int cp  = tid >> 2;         // channel pair 0..127
        const float* Xa = X + (size_t)(cp * 2) * TT;
        const float* Xb = Xa + TT;
        #pragma unroll
        for (int it = 0; it < 4; ++it) {  // rows 0..63
            int tg = tg0 + it * 16 + tc4 * 4;
            f32x4 va = (f32x4){0.f,0.f,0.f,0.f}, vb = va;
            if (tg >= 0) { va = *(const f32x4*)&Xa[tg]; vb = *(const f32x4*)&Xb[tg]; }
            #pragma unroll
            for (int e = 0; e < 4; ++e) {
                int row = it * 16 + tc4 * 4 + e;
                unsigned pk = (unsigned)f2b(va[e]) | ((unsigned)f2b(vb[e]) << 16);
                *(unsigned*)(lds + swz(row, cp * 4)) = pk;
            }
        }
        // tail rows 64..71 = tokens t0+56..t0+63 (always in range)
        int c = tid & 255, h = tid >> 8;  // h 0..1, 4 rows each
        f32x4 v = *(const f32x4*)&X[(size_t)c * TT + tg0 + 64 + h * 4];
        #pragma unroll
        for (int e = 0; e < 4; ++e)
            *(ushort*)(lds + swz(64 + h * 4 + e, c * 2)) = f2b(v[e]);
    }
    __syncthreads();

    const int ws = tid >> 6, lane = tid & 63;   // ws = channel stripe 0..7
    const int l16 = lane & 15, quad = lane >> 4;
    // B-operand rows: cn 0/1 = filter ch, cn 2/3 = gate ch (paired with 0/1)
    int mrow[4];
    mrow[0] = ws * 32 + l16;        mrow[1] = ws * 32 + 16 + l16;
    mrow[2] = 256 + mrow[0];        mrow[3] = 256 + mrow[1];
    const ushort* W1p[4];
    const ushort* W2p[4];
    #pragma unroll
    for (int cn = 0; cn < 4; ++cn) {
        W1p[cn] = W1 + (size_t)mrow[cn] * 512 + quad * 8;
        W2p[cn] = W2 + (size_t)mrow[cn] * 256 + quad * 8;
    }

    // ---------------- GEMM1: acc[token-tile][ch-tile] over K=512 ----------------
    f32x4 acc[4][4];
    #pragma unroll
    for (int i = 0; i < 4; ++i)
        #pragma unroll
        for (int j = 0; j < 4; ++j) acc[i][j] = (f32x4){0.f,0.f,0.f,0.f};

    #pragma unroll
    for (int kq = 0; kq < 16; ++kq) {
        const int tap = kq >> 3, ci = kq & 7;
        s16x8 xf[4];
        #pragma unroll
        for (int tm = 0; tm < 4; ++tm)
            xf[tm] = *(const s16x8*)(lds + swz(tm * 16 + l16 + 8 * tap,
                                              ci * 64 + quad * 16));
        #pragma unroll
        for (int cn = 0; cn < 4; ++cn) {
            s16x8 w = *(const s16x8*)&W1p[cn][kq * 32];   // imm-offset L2 load
            #pragma unroll
            for (int tm = 0; tm < 4; ++tm)
                acc[tm][cn] = __builtin_amdgcn_mfma_f32_16x16x32_bf16(xf[tm], w, acc[tm][cn], 0, 0, 0);
        }
    }
    __syncthreads();   // all GEMM1 LDS reads done before z overwrites rows 0..63

    // ---------------- activations -> z (bf16) rows 0..63 ----------------
    #pragma unroll
    for (int cn = 0; cn < 2; ++cn) {
        const int zc = ws * 32 + cn * 16 + l16;
        const float bfv = b_filt[zc], bgv = b_gate[zc];
        #pragma unroll
        for (int tm = 0; tm < 4; ++tm) {
            #pragma unroll
            for (int r = 0; r < 4; ++r) {
                float fv = acc[tm][cn][r]     + bfv;
                float gv = acc[tm][cn + 2][r] + bgv;
                int row = tm * 16 + quad * 4 + r;
                *(ushort*)(lds + swz(row, zc * 2)) = f2b(fast_tanh(fv) * fast_sigmoid(gv));
            }
        }
    }
    __syncthreads();

    // ---------------- GEMM2 over K=256 (reuse acc registers) ----------------
    #pragma unroll
    for (int i = 0; i < 4; ++i)
        #pragma unroll
        for (int j = 0; j < 4; ++j) acc[i][j] = (f32x4){0.f,0.f,0.f,0.f};

    #pragma unroll
    for (int kq = 0; kq < 8; ++kq) {
        s16x8 zf[4];
        #pragma unroll
        for (int tm = 0; tm < 4; ++tm)
            zf[tm] = *(const s16x8*)(lds + swz(tm * 16 + l16, kq * 64 + quad * 16));
        #pragma unroll
        for (int cn = 0; cn < 4; ++cn) {
            s16x8 w = *(const s16x8*)&W2p[cn][kq * 32];
            #pragma unroll
            for (int tm = 0; tm < 4; ++tm)
                acc[tm][cn] = __builtin_amdgcn_mfma_f32_16x16x32_bf16(zf[tm], w, acc[tm][cn], 0, 0, 0);
        }
    }

    // ---------------- epilogue: vectorized f32x4 stores ----------------
    const size_t OUT1 = (size_t)NB * CH * TT;
    #pragma unroll
    for (int cn = 0; cn < 2; ++cn) {
        const int ch = ws * 32 + cn * 16 + l16;
        const float br = b_res[ch], bs = b_skip[ch];
        const float* Xc = X + (size_t)ch * TT + t0;
        float* O0 = out + ((size_t)(b * CH + ch)) * TT + t0;
        float* O1 = O0 + OUT1;
        #pragma unroll
        for (int tm = 0; tm < 4; ++tm) {
            const int ttk = tm * 16 + quad * 4;
            f32x4 xv = *(const f32x4*)&Xc[ttk];   // exact f32 x (L2-hot)
            f32x4 o0, o1;
            #pragma unroll
            for (int r = 0; r < 4; ++r) {
                o0[r] = xv[r] + acc[tm][cn][r] + br;
                o1[r] = acc[tm][cn + 2][r] + bs;
            }
            *(f32x4*)&O0[ttk] = o0;
            *(f32x4*)&O1[ttk] = o1;
        }
    }
}

extern "C" void kernel_launch(void* const* d_in, const int* in_sizes, int n_in,
                              void* d_out, int out_size, void* d_ws, size_t ws_size,
                              hipStream_t stream) {
    const float* x   = (const float*)d_in[0];
    const float* wf  = (const float*)d_in[1];
    const float* bfi = (const float*)d_in[2];
    const float* wg  = (const float*)d_in[3];
    const float* bg  = (const float*)d_in[4];
    const float* wr  = (const float*)d_in[5];
    const float* br  = (const float*)d_in[6];
    const float* wsk = (const float*)d_in[7];
    const float* bs  = (const float*)d_in[8];

    ushort* W1 = (ushort*)d_ws;                  // 512*512 bf16
    ushort* W2 = W1 + 512 * 512;                 // 512*256 bf16

    prep_w<<<128, 512, 0, stream>>>(wf, wg, wr, wsk, W1, W2);

    const int nBlocks = NB * (TT / NT);          // 1024
    fused_block<<<nBlocks, 512, 0, stream>>>(x, W1, W2, bfi, bg, br, bs,
                                             (float*)d_out);
}

// Round 6
// 256.349 us; speedup vs baseline: 1.1764x; 1.1764x over previous
//
#include <hip/hip_runtime.h>

using f32x4 = __attribute__((ext_vector_type(4))) float;
using f32x2 = __attribute__((ext_vector_type(2))) float;
using s16x8 = __attribute__((ext_vector_type(8))) short;
using u16x4 = __attribute__((ext_vector_type(4))) ushort;

constexpr int NB   = 16;    // batch
constexpr int CH   = 256;   // channels
constexpr int TT   = 4096;  // time
constexpr int NT   = 128;   // tokens per tile
constexpr int HALO = 8;     // (K-1)*DIL
constexpr int XROWS = NT + HALO;     // 136
// pitch 528B = 512 + 16: row stride mod 128B = 16 -> 16 consecutive rows
// cover all 8 16B bank slots (2-way aliasing = free, same as XOR swizzle)
// while keeping PLAIN addressing: every ds_read offset is base + immediate.
constexpr int ROWB = 528;
constexpr int XBYTES = XROWS * ROWB;   // 71808
constexpr int ZOFF   = XBYTES;         // z buffer: 128 rows
constexpr int ZBYTES = NT * ROWB;      // 67584
// total LDS = 139392 B -> 1 block/CU (register-forced anyway)

__device__ __forceinline__ ushort f2b(float f) {
    unsigned u; __builtin_memcpy(&u, &f, 4);
    u += 0x7FFFu + ((u >> 16) & 1u);   // RNE
    return (ushort)(u >> 16);
}
__device__ __forceinline__ float fast_sigmoid(float x) {
    return __builtin_amdgcn_rcpf(1.f + __expf(-x));
}
__device__ __forceinline__ float fast_tanh(float x) {
    return 2.f * __builtin_amdgcn_rcpf(1.f + __expf(-2.f * x)) - 1.f;
}

// Weight prep: f32 -> bf16.
// W1[m][k]: m<256 filter / m>=256 gate, k = tap*256 + in_ch.
// W2[m][i]: m<256 res / m>=256 skip.
__global__ __launch_bounds__(512)
void prep_w(const float* __restrict__ wf, const float* __restrict__ wg,
            const float* __restrict__ wr, const float* __restrict__ wsk,
            ushort* __restrict__ W1, ushort* __restrict__ W2) {
    int g = blockIdx.x * 512 + threadIdx.x;
    if (g < 512 * 64) {                       // W1: 512 rows x 64 threads (4 i each)
        int m = g >> 6, i0 = (g & 63) * 4;
        const float* src = (m < 256) ? wf + ((size_t)m << 9)
                                     : wg + ((size_t)(m - 256) << 9);
        f32x4 a = *(const f32x4*)&src[i0 * 2];
        f32x4 c = *(const f32x4*)&src[i0 * 2 + 4];
        u16x4 t0v = { f2b(a[0]), f2b(a[2]), f2b(c[0]), f2b(c[2]) };
        u16x4 t1v = { f2b(a[1]), f2b(a[3]), f2b(c[1]), f2b(c[3]) };
        *(u16x4*)&W1[(size_t)m * 512 + i0]       = t0v;   // tap 0 block
        *(u16x4*)&W1[(size_t)m * 512 + 256 + i0] = t1v;   // tap 1 block
    } else {                                  // W2: 512 rows x 64 threads
        int g2 = g - 512 * 64;
        int m = g2 >> 6, i0 = (g2 & 63) * 4;
        const float* src = (m < 256) ? wr + ((size_t)m << 8)
                                     : wsk + ((size_t)(m - 256) << 8);
        f32x4 a = *(const f32x4*)&src[i0];
        u16x4 o = { f2b(a[0]), f2b(a[1]), f2b(a[2]), f2b(a[3]) };
        *(u16x4*)&W2[(size_t)m * 256 + i0] = o;
    }
}

// 512 blocks x 1024 threads (16 waves, 4/SIMD). Wave w owns output channels
// [w*16, w*16+16): filter rows + paired gate rows. acc[8][2] = 64 AGPR.
// All GEMM LDS reads: ONE base VGPR + immediate offsets (pitch-528 layout).
// z has its own LDS region -> no barrier between GEMM1 and activations.
// MFMA roles: A = x-fragment (M=16 tokens), B = W-fragment (N=16 out-ch)
// => D: row = quad*4+r = token, col = lane&15 = channel.
__global__ __launch_bounds__(1024, 4)
void fused_block(const float* __restrict__ x,
                 const ushort* __restrict__ W1, const ushort* __restrict__ W2,
                 const float* __restrict__ b_filt, const float* __restrict__ b_gate,
                 const float* __restrict__ b_res,  const float* __restrict__ b_skip,
                 float* __restrict__ out) {
    __shared__ __align__(16) char lds[XBYTES + ZBYTES];   // 139392 B

    const int tid = threadIdx.x;
    const int b  = blockIdx.x >> 5;           // 32 tiles per batch
    const int t0 = (blockIdx.x & 31) * NT;
    const float* X = x + (size_t)b * CH * TT;
    const int tg0 = t0 - HALO;

    // ---------------- stage x (f32 -> bf16, transposed) ----------------
    {
        const int tc  = tid & 7;          // token chunk (4 tokens) within 32
        const int cp  = tid >> 3;         // channel pair 0..127
        const float* Xa = X + (size_t)(cp * 2) * TT;
        const float* Xb = Xa + TT;
        #pragma unroll
        for (int it = 0; it < 4; ++it) {  // rows 0..127
            int tg = tg0 + it * 32 + tc * 4;
            f32x4 va = (f32x4){0.f,0.f,0.f,0.f}, vb = va;
            if (tg >= 0) { va = *(const f32x4*)&Xa[tg]; vb = *(const f32x4*)&Xb[tg]; }
            #pragma unroll
            for (int e = 0; e < 4; ++e) {
                int row = it * 32 + tc * 4 + e;
                unsigned pk = (unsigned)f2b(va[e]) | ((unsigned)f2b(vb[e]) << 16);
                *(unsigned*)(lds + row * ROWB + cp * 4) = pk;
            }
        }
        // tail rows 128..135 = tokens t0+120..t0+127 (always in range)
        int c = tid & 255, h = tid >> 8;  // h 0..3 -> 2 tokens each
        f32x2 v = *(const f32x2*)&X[(size_t)c * TT + tg0 + 128 + h * 2];
        #pragma unroll
        for (int e = 0; e < 2; ++e)
            *(ushort*)(lds + (128 + h * 2 + e) * ROWB + c * 2) = f2b(v[e]);
    }
    __syncthreads();

    const int wv = tid >> 6, lane = tid & 63;
    const int l16 = lane & 15, quad = lane >> 4;
    const int ch16 = wv * 16;             // this wave's 16-channel stripe
    const ushort* W1F = W1 + (size_t)(ch16 + l16) * 512 + quad * 8;
    const ushort* W1G = W1F + (size_t)256 * 512;          // gate rows
    const ushort* W2F = W2 + (size_t)(ch16 + l16) * 256 + quad * 8;
    const ushort* W2G = W2F + (size_t)256 * 256;          // skip rows

    // single base VGPR for all GEMM1 LDS reads; imm = tm*8448 + tap*4224 + ci*64
    const char* xbase = lds + l16 * ROWB + quad * 16;
    // single base for GEMM2; imm = tm*8448 + kq*64
    const char* zbase = lds + ZOFF + l16 * ROWB + quad * 16;

    // ---------------- GEMM1: acc[token-tile][f/g] over K=512 ----------------
    f32x4 acc[8][2];
    #pragma unroll
    for (int i = 0; i < 8; ++i) { acc[i][0] = (f32x4){0.f,0.f,0.f,0.f};
                                  acc[i][1] = (f32x4){0.f,0.f,0.f,0.f}; }

    s16x8 wcF = *(const s16x8*)&W1F[0];
    s16x8 wcG = *(const s16x8*)&W1G[0];

    #pragma unroll
    for (int kq = 0; kq < 16; ++kq) {
        s16x8 wnF, wnG;
        if (kq < 15) {                       // distance-1 prefetch (L2-hot)
            wnF = *(const s16x8*)&W1F[(kq + 1) * 32];
            wnG = *(const s16x8*)&W1G[(kq + 1) * 32];
        }
        const int tap = kq >> 3, ci = kq & 7;
        #pragma unroll
        for (int g = 0; g < 4; ++g) {        // token-tiles in pairs
            s16x8 xf0 = *(const s16x8*)(xbase + (2*g)   * 8448 + tap * 4224 + ci * 64);
            s16x8 xf1 = *(const s16x8*)(xbase + (2*g+1) * 8448 + tap * 4224 + ci * 64);
            acc[2*g][0]   = __builtin_amdgcn_mfma_f32_16x16x32_bf16(xf0, wcF, acc[2*g][0],   0, 0, 0);
            acc[2*g][1]   = __builtin_amdgcn_mfma_f32_16x16x32_bf16(xf0, wcG, acc[2*g][1],   0, 0, 0);
            acc[2*g+1][0] = __builtin_amdgcn_mfma_f32_16x16x32_bf16(xf1, wcF, acc[2*g+1][0], 0, 0, 0);
            acc[2*g+1][1] = __builtin_amdgcn_mfma_f32_16x16x32_bf16(xf1, wcG, acc[2*g+1][1], 0, 0, 0);
        }
        if (kq < 15) { wcF = wnF; wcG = wnG; }
    }

    // preload GEMM2's first W fragments; L2 latency hides under activations
    s16x8 wc2F = *(const s16x8*)&W2F[0];
    s16x8 wc2G = *(const s16x8*)&W2G[0];

    // NO barrier here: z region is disjoint from x region, and activations
    // consume only this wave's own accumulators.

    // ---------------- activations -> z (bf16), separate LDS region ----------------
    {
        const int zc = ch16 + l16;
        const float bfv = b_filt[zc], bgv = b_gate[zc];
        #pragma unroll
        for (int tm = 0; tm < 8; ++tm) {
            #pragma unroll
            for (int r = 0; r < 4; ++r) {
                float fv = acc[tm][0][r] + bfv;
                float gv = acc[tm][1][r] + bgv;
                int row = tm * 16 + quad * 4 + r;
                *(ushort*)(lds + ZOFF + row * ROWB + zc * 2) =
                    f2b(fast_tanh(fv) * fast_sigmoid(gv));
            }
        }
    }
    __syncthreads();   // all z written before GEMM2 reads all channels

    // ---------------- GEMM2 over K=256 (reuse acc registers) ----------------
    #pragma unroll
    for (int i = 0; i < 8; ++i) { acc[i][0] = (f32x4){0.f,0.f,0.f,0.f};
                                  acc[i][1] = (f32x4){0.f,0.f,0.f,0.f}; }

    #pragma unroll
    for (int kq = 0; kq < 8; ++kq) {
        s16x8 wn2F, wn2G;
        if (kq < 7) {
            wn2F = *(const s16x8*)&W2F[(kq + 1) * 32];
            wn2G = *(const s16x8*)&W2G[(kq + 1) * 32];
        }
        #pragma unroll
        for (int g = 0; g < 4; ++g) {
            s16x8 zf0 = *(const s16x8*)(zbase + (2*g)   * 8448 + kq * 64);
            s16x8 zf1 = *(const s16x8*)(zbase + (2*g+1) * 8448 + kq * 64);
            acc[2*g][0]   = __builtin_amdgcn_mfma_f32_16x16x32_bf16(zf0, wc2F, acc[2*g][0],   0, 0, 0);
            acc[2*g][1]   = __builtin_amdgcn_mfma_f32_16x16x32_bf16(zf0, wc2G, acc[2*g][1],   0, 0, 0);
            acc[2*g+1][0] = __builtin_amdgcn_mfma_f32_16x16x32_bf16(zf1, wc2F, acc[2*g+1][0], 0, 0, 0);
            acc[2*g+1][1] = __builtin_amdgcn_mfma_f32_16x16x32_bf16(zf1, wc2G, acc[2*g+1][1], 0, 0, 0);
        }
        if (kq < 7) { wc2F = wn2F; wc2G = wn2G; }
    }

    // ---------------- epilogue: vectorized f32x4 stores ----------------
    const size_t OUT1 = (size_t)NB * CH * TT;
    {
        const int ch = ch16 + l16;
        const float br = b_res[ch], bs = b_skip[ch];
        const float* Xc = X + (size_t)ch * TT + t0;
        float* O0 = out + ((size_t)(b * CH + ch)) * TT + t0;
        float* O1 = O0 + OUT1;
        #pragma unroll
        for (int tm = 0; tm < 8; ++tm) {
            const int ttk = tm * 16 + quad * 4;
            f32x4 xv = *(const f32x4*)&Xc[ttk];   // exact f32 x (L2-hot)
            f32x4 o0, o1;
            #pragma unroll
            for (int r = 0; r < 4; ++r) {
                o0[r] = xv[r] + acc[tm][0][r] + br;
                o1[r] = acc[tm][1][r] + bs;
            }
            *(f32x4*)&O0[ttk] = o0;
            *(f32x4*)&O1[ttk] = o1;
        }
    }
}

extern "C" void kernel_launch(void* const* d_in, const int* in_sizes, int n_in,
                              void* d_out, int out_size, void* d_ws, size_t ws_size,
                              hipStream_t stream) {
    const float* x   = (const float*)d_in[0];
    const float* wf  = (const float*)d_in[1];
    const float* bfi = (const float*)d_in[2];
    const float* wg  = (const float*)d_in[3];
    const float* bg  = (const float*)d_in[4];
    const float* wr  = (const float*)d_in[5];
    const float* br  = (const float*)d_in[6];
    const float* wsk = (const float*)d_in[7];
    const float* bs  = (const float*)d_in[8];

    ushort* W1 = (ushort*)d_ws;                  // 512*512 bf16
    ushort* W2 = W1 + 512 * 512;                 // 512*256 bf16

    prep_w<<<128, 512, 0, stream>>>(wf, wg, wr, wsk, W1, W2);

    const int nBlocks = NB * (TT / NT);          // 512
    fused_block<<<nBlocks, 1024, 0, stream>>>(x, W1, W2, bfi, bg, br, bs,
                                              (float*)d_out);
}